// Round 1
// baseline (2918.978 us; speedup 1.0000x reference)
//
#include <hip/hip_runtime.h>

#define N_ATOMS 50000
#define N_PAIRS 800000
#define F 128

// ---------------------------------------------------------------------------
// Kernel 1: out = concat(q, mu)  (out is re-poisoned before every launch)
// ---------------------------------------------------------------------------
__global__ __launch_bounds__(256) void init_out_kernel(
    const float4* __restrict__ q4, const float4* __restrict__ mu4,
    float4* __restrict__ out4) {
  long idx = (long)blockIdx.x * 256 + threadIdx.x;
  const long nq4   = (long)N_ATOMS * F / 4;      // 1.6M float4
  const long ntot4 = (long)N_ATOMS * 4 * F / 4;  // 6.4M float4
  if (idx >= ntot4) return;
  float4 v = (idx < nq4) ? q4[idx] : mu4[idx - nq4];
  out4[idx] = v;
}

// ---------------------------------------------------------------------------
// Kernel 2: qT[f][n] = q[n][f]   (LDS-tiled 32x32 transpose, coalesced both sides)
// ---------------------------------------------------------------------------
__global__ __launch_bounds__(256) void transpose_q_kernel(
    const float* __restrict__ q, float* __restrict__ qT) {
  __shared__ float tile[32][33];
  int f0 = blockIdx.y * 32;  // feature block (F=128 -> gridDim.y = 4)
  int n0 = blockIdx.x * 32;  // atom block
  int tx = threadIdx.x & 31;
  int ty = threadIdx.x >> 5;  // 0..7
#pragma unroll
  for (int k = 0; k < 32; k += 8) {
    int n = n0 + ty + k;
    tile[ty + k][tx] = (n < N_ATOMS) ? q[(long)n * F + f0 + tx] : 0.f;
  }
  __syncthreads();
  int n = n0 + tx;
  if (n < N_ATOMS) {
#pragma unroll
    for (int k = 0; k < 32; k += 8) {
      qT[(long)(f0 + ty + k) * N_ATOMS + n] = tile[tx][ty + k];
    }
  }
}

// ---------------------------------------------------------------------------
// Kernel 3: hT[g][n] = silu(sum_f q[n][f]*W1[g][f] + b1[g])
//   thread <-> atom (lane-coalesced qT reads), W1 index wave-uniform -> s_load
// ---------------------------------------------------------------------------
#define GB1 32
__global__ __launch_bounds__(256) void mlp1_kernel(
    const float* __restrict__ qT, const float* __restrict__ W1,
    const float* __restrict__ b1, float* __restrict__ hT) {
  int a  = blockIdx.x * 256 + threadIdx.x;
  int g0 = blockIdx.y * GB1;
  bool valid = (a < N_ATOMS);
  int ac = valid ? a : 0;
  float acc[GB1];
#pragma unroll
  for (int i = 0; i < GB1; i++) acc[i] = 0.f;
#pragma unroll 4
  for (int f = 0; f < F; f++) {
    float qv = qT[(long)f * N_ATOMS + ac];
#pragma unroll
    for (int i = 0; i < GB1; i++)
      acc[i] = fmaf(qv, W1[(g0 + i) * F + f], acc[i]);
  }
  if (valid) {
#pragma unroll
    for (int i = 0; i < GB1; i++) {
      float v = acc[i] + b1[g0 + i];
      hT[(long)(g0 + i) * N_ATOMS + a] = v / (1.f + __expf(-v));  // silu
    }
  }
}

// ---------------------------------------------------------------------------
// Kernel 4: x[n][go] = sum_f h[n][f]*W2[go][f] + b2[go],  go in [0,384)
// ---------------------------------------------------------------------------
#define GB2 48
__global__ __launch_bounds__(256) void mlp2_kernel(
    const float* __restrict__ hT, const float* __restrict__ W2,
    const float* __restrict__ b2, float* __restrict__ x) {
  int a  = blockIdx.x * 256 + threadIdx.x;
  int g0 = blockIdx.y * GB2;
  bool valid = (a < N_ATOMS);
  int ac = valid ? a : 0;
  float acc[GB2];
#pragma unroll
  for (int i = 0; i < GB2; i++) acc[i] = 0.f;
#pragma unroll 2
  for (int f = 0; f < F; f++) {
    float hv = hT[(long)f * N_ATOMS + ac];
#pragma unroll
    for (int i = 0; i < GB2; i++)
      acc[i] = fmaf(hv, W2[(g0 + i) * F + f], acc[i]);
  }
  if (valid) {
    float* xp = x + (long)a * (3 * F) + g0;
#pragma unroll
    for (int i = 0; i < GB2; i += 4) {
      float4 v = make_float4(acc[i]     + b2[g0 + i],
                             acc[i + 1] + b2[g0 + i + 1],
                             acc[i + 2] + b2[g0 + i + 2],
                             acc[i + 3] + b2[g0 + i + 3]);
      *(float4*)(xp + i) = v;
    }
  }
}

// ---------------------------------------------------------------------------
// Kernel 5: pair phase. 128 threads per pair (2 pairs per 256-thread block).
//   xw = Wij * x[j]; dq = xw[0:F]; dmuR = xw[F:2F]; dmumu = xw[2F:3F]
//   out_q[i]      += dq
//   out_mu[i][d]  += dmuR*dir[d] + dmumu*mu[j][d]
// Wij is streamed exactly once -> non-temporal loads so it doesn't evict the
// L2/L3-resident x and mu gather working sets.
// ---------------------------------------------------------------------------
__global__ __launch_bounds__(256) void pair_kernel(
    const float* __restrict__ Wij, const float* __restrict__ dir_ij,
    const int* __restrict__ pl, const float* __restrict__ mu,
    const float* __restrict__ x, float* __restrict__ out) {
  int pr = blockIdx.x * 2 + (threadIdx.x >> 7);
  int f  = threadIdx.x & (F - 1);
  int i = pl[pr];
  int j = pl[N_PAIRS + pr];
  const float* w  = Wij + (long)pr * (3 * F);
  const float* xj = x   + (long)j  * (3 * F);
  const float* mj = mu  + (long)j  * (3 * F);
  float wq = __builtin_nontemporal_load(w + f);
  float wR = __builtin_nontemporal_load(w + F + f);
  float wM = __builtin_nontemporal_load(w + 2 * F + f);
  float dq = wq * xj[f];
  float aR = wR * xj[F + f];
  float aM = wM * xj[2 * F + f];
  float d0 = dir_ij[pr * 3 + 0];
  float d1 = dir_ij[pr * 3 + 1];
  float d2 = dir_ij[pr * 3 + 2];
  float* oq = out;
  float* om = out + (long)N_ATOMS * F;
  atomicAdd(oq + (long)i * F + f, dq);
  atomicAdd(om + (long)i * (3 * F) + f,         fmaf(aR, d0, aM * mj[f]));
  atomicAdd(om + (long)i * (3 * F) + F + f,     fmaf(aR, d1, aM * mj[F + f]));
  atomicAdd(om + (long)i * (3 * F) + 2 * F + f, fmaf(aR, d2, aM * mj[2 * F + f]));
}

// ---------------------------------------------------------------------------
extern "C" void kernel_launch(void* const* d_in, const int* in_sizes, int n_in,
                              void* d_out, int out_size, void* d_ws, size_t ws_size,
                              hipStream_t stream) {
  const float* q   = (const float*)d_in[0];
  const float* mu  = (const float*)d_in[1];
  const float* Wij = (const float*)d_in[2];
  const float* dir = (const float*)d_in[3];
  const int*   pl  = (const int*)d_in[4];
  const float* W1  = (const float*)d_in[5];
  const float* b1  = (const float*)d_in[6];
  const float* W2  = (const float*)d_in[7];
  const float* b2  = (const float*)d_in[8];
  float* out = (float*)d_out;

  // workspace layout (floats): x[19.2M] | hT[6.4M] | qT[6.4M]  => 128 MB
  float* ws = (float*)d_ws;
  float* x  = ws;
  float* hT = ws + (long)N_ATOMS * 3 * F;
  float* qT = hT + (long)N_ATOMS * F;

  // out init (independent of MLP chain)
  hipLaunchKernelGGL(init_out_kernel, dim3((N_ATOMS * 4 * F / 4 + 255) / 256),
                     dim3(256), 0, stream,
                     (const float4*)q, (const float4*)mu, (float4*)out);
  // MLP chain
  hipLaunchKernelGGL(transpose_q_kernel, dim3((N_ATOMS + 31) / 32, F / 32),
                     dim3(256), 0, stream, q, qT);
  hipLaunchKernelGGL(mlp1_kernel, dim3((N_ATOMS + 255) / 256, F / GB1),
                     dim3(256), 0, stream, qT, W1, b1, hT);
  hipLaunchKernelGGL(mlp2_kernel, dim3((N_ATOMS + 255) / 256, 3 * F / GB2),
                     dim3(256), 0, stream, hT, W2, b2, x);
  // pair scatter
  hipLaunchKernelGGL(pair_kernel, dim3(N_PAIRS / 2), dim3(256), 0, stream,
                     Wij, dir, pl, mu, x, out);
}